// Round 17
// baseline (277.156 us; speedup 1.0000x reference)
//
#include <hip/hip_runtime.h>
#include <hip/hip_fp16.h>

#define NF 16          // feature width of h / output
#define FI 8           // input feature width
#define NPB 64         // nodes per bucket
#define BSH 6          // log2(NPB)
#define CHUNK 4096     // edges per partition chunk (fits LDS staging)
#define MAXNB 1600     // max buckets supported by LDS tables (NB=1563)
#define CAPB 6144      // max edges per bucket staged in degv LDS (mean 4096, sigma 64)
#define PT 1024        // pscatter/phist threads

// ---------------------------------------------------------------------------
// h1 = x @ W1  -> fp16 packed rows, UNscaled (degv scales by dinv later)
// ---------------------------------------------------------------------------
__global__ void k_h1(const float* __restrict__ x, const float* __restrict__ W1,
                     __half* __restrict__ h16, int n) {
    int i = blockIdx.x * blockDim.x + threadIdx.x;
    if (i >= n) return;
    const float4* xp = reinterpret_cast<const float4*>(x + (size_t)i * FI);
    float4 a = xp[0], b = xp[1];
    float xi[FI] = {a.x, a.y, a.z, a.w, b.x, b.y, b.z, b.w};
    float o[NF];
    #pragma unroll
    for (int f = 0; f < NF; ++f) {
        float acc = 0.f;
        #pragma unroll
        for (int k = 0; k < FI; ++k) acc = fmaf(xi[k], W1[k * NF + f], acc);
        o[f] = acc;
    }
    union { __half2 h2[8]; float4 v4[2]; } u;
    #pragma unroll
    for (int q = 0; q < 8; ++q) u.h2[q] = __floats2half2_rn(o[2 * q], o[2 * q + 1]);
    float4* hp = reinterpret_cast<float4*>(h16 + (size_t)i * NF);
    hp[0] = u.v4[0];
    hp[1] = u.v4[1];
}

// h2 = relu(src_f32) @ W2, scaled by dinv -> fp16 packed rows (h' = h2*dinv)
__global__ void k_h2(const float* __restrict__ src, const float* __restrict__ W2,
                     const float* __restrict__ dinv, __half* __restrict__ h16, int n) {
    int i = blockIdx.x * blockDim.x + threadIdx.x;
    if (i >= n) return;
    float hi[NF];
    const float4* ip = reinterpret_cast<const float4*>(src + (size_t)i * NF);
    #pragma unroll
    for (int q = 0; q < 4; ++q) {
        float4 v = ip[q];
        hi[q * 4 + 0] = fmaxf(v.x, 0.f);
        hi[q * 4 + 1] = fmaxf(v.y, 0.f);
        hi[q * 4 + 2] = fmaxf(v.z, 0.f);
        hi[q * 4 + 3] = fmaxf(v.w, 0.f);
    }
    float di = dinv[i];
    float o[NF];
    #pragma unroll
    for (int f = 0; f < NF; ++f) {
        float acc = 0.f;
        #pragma unroll
        for (int k = 0; k < NF; ++k) acc = fmaf(hi[k], W2[k * NF + f], acc);
        o[f] = acc * di;
    }
    union { __half2 h2[8]; float4 v4[2]; } u;
    #pragma unroll
    for (int q = 0; q < 8; ++q) u.h2[q] = __floats2half2_rn(o[2 * q], o[2 * q + 1]);
    float4* hp = reinterpret_cast<float4*>(h16 + (size_t)i * NF);
    hp[0] = u.v4[0];
    hp[1] = u.v4[1];
}

// ======================= radix-partition CSR build =========================
// table: u16, chunk-major table[chunk*NB + b]. Counts <= CHUNK; scanned
// offsets <= btot (~4400 for this input; assumption btot < 65536).

__global__ void k_phist(const int* __restrict__ col, unsigned short* __restrict__ table,
                        int NB, int E) {
    __shared__ int lh[MAXNB];
    int chunk = blockIdx.x, t = threadIdx.x;
    int c0 = chunk * CHUNK;
    int m = min(CHUNK, E - c0);
    for (int i = t; i < NB; i += PT) lh[i] = 0;
    __syncthreads();
    const int4* col4 = reinterpret_cast<const int4*>(col + c0);
    int m4 = m >> 2;
    for (int i = t; i < m4; i += PT) {
        int4 v = col4[i];
        atomicAdd(&lh[v.x >> BSH], 1);
        atomicAdd(&lh[v.y >> BSH], 1);
        atomicAdd(&lh[v.z >> BSH], 1);
        atomicAdd(&lh[v.w >> BSH], 1);
    }
    for (int i = (m4 << 2) + t; i < m; i += PT)
        atomicAdd(&lh[col[c0 + i] >> BSH], 1);
    __syncthreads();
    for (int b = t; b < NB; b += PT)
        table[(size_t)chunk * NB + b] = (unsigned short)lh[b];
}

// grid = NB blocks: exclusive scan of column b over NC chunks, shfl-based
__global__ void k_scan_chunks(unsigned short* __restrict__ table, int* __restrict__ btot,
                              int NB, int NC) {
    __shared__ int wsum[16];
    int b = blockIdx.x, t = threadIdx.x;
    int i0 = 2 * t, i1 = 2 * t + 1;
    int a = (i0 < NC) ? (int)table[(size_t)i0 * NB + b] : 0;
    int c = (i1 < NC) ? (int)table[(size_t)i1 * NB + b] : 0;
    int val = a + c;
    int lane = t & 63, wv = t >> 6;
    int inc = val;
    #pragma unroll
    for (int d = 1; d < 64; d <<= 1) {
        int o = __shfl_up(inc, d);
        if (lane >= d) inc += o;
    }
    if (lane == 63) wsum[wv] = inc;
    __syncthreads();
    if (t < 16) {
        int v = wsum[t];
        int in2 = v;
        #pragma unroll
        for (int d = 1; d < 16; d <<= 1) {
            int o = __shfl_up(in2, d);
            if (t >= d) in2 += o;
        }
        wsum[t] = in2 - v;   // exclusive
    }
    __syncthreads();
    int excl = wsum[wv] + inc - val;
    if (i0 < NC) table[(size_t)i0 * NB + b] = (unsigned short)excl;
    if (i1 < NC) table[(size_t)i1 * NB + b] = (unsigned short)(excl + a);
    if (t == 1023) btot[b] = excl + val;
}

// exclusive scan over bucket totals, shfl-based (2 elems/thread, NB<=2048)
__global__ void k_scan_buckets(const int* __restrict__ btot, int* __restrict__ bstart,
                               int NB) {
    __shared__ int wsum[16];
    int t = threadIdx.x;   // blockDim = 1024
    int i0 = 2 * t, i1 = 2 * t + 1;
    int a = (i0 < NB) ? btot[i0] : 0;
    int b = (i1 < NB) ? btot[i1] : 0;
    int val = a + b;
    int lane = t & 63, wv = t >> 6;
    int inc = val;
    #pragma unroll
    for (int d = 1; d < 64; d <<= 1) {
        int o = __shfl_up(inc, d);
        if (lane >= d) inc += o;
    }
    if (lane == 63) wsum[wv] = inc;
    __syncthreads();
    if (t < 16) {
        int v = wsum[t];
        int in2 = v;
        #pragma unroll
        for (int d = 1; d < 16; d <<= 1) {
            int o = __shfl_up(in2, d);
            if (t >= d) in2 += o;
        }
        wsum[t] = in2 - v;
    }
    __syncthreads();
    int excl = wsum[wv] + inc - val;
    if (i0 < NB) bstart[i0] = excl;
    if (i1 < NB) bstart[i1] = excl + a;
}

// partition scatter with in-LDS counting sort; flush in ascending global
// order with PLAIN stores (L2 merges cross-block runs — round 13 lesson).
// part[p] = { low32 = row | (col_local << 25), high32 = w bits }
__global__ __launch_bounds__(PT)
void k_pscatter(const int* __restrict__ row, const int* __restrict__ col,
                const float* __restrict__ w, const unsigned short* __restrict__ table,
                const int* __restrict__ bstart, float2* __restrict__ part,
                int NB, int E) {
    __shared__ long long st2[CHUNK];         // 32 KB
    __shared__ unsigned short bkt[CHUNK];    // 8 KB
    __shared__ int off[MAXNB], cur[MAXNB], gbase[MAXNB];  // 3 x 6.4 KB
    __shared__ int wsum[16];
    int chunk = blockIdx.x, t = threadIdx.x;
    int c0 = chunk * CHUNK;
    int m = min(CHUNK, E - c0);

    for (int i = t; i < NB; i += PT) cur[i] = 0;
    __syncthreads();
    for (int i = t; i < m; i += PT)
        atomicAdd(&cur[col[c0 + i] >> BSH], 1);
    __syncthreads();
    int i0 = 2 * t, i1 = 2 * t + 1;
    int a = (i0 < NB) ? cur[i0] : 0;
    int b = (i1 < NB) ? cur[i1] : 0;
    int val = a + b;
    int lane = t & 63, wv = t >> 6;
    int inc = val;
    #pragma unroll
    for (int d = 1; d < 64; d <<= 1) {
        int o = __shfl_up(inc, d);
        if (lane >= d) inc += o;
    }
    if (lane == 63) wsum[wv] = inc;
    __syncthreads();
    if (t < 16) {
        int v = wsum[t];
        int in2 = v;
        #pragma unroll
        for (int d = 1; d < 16; d <<= 1) {
            int o = __shfl_up(in2, d);
            if (t >= d) in2 += o;
        }
        wsum[t] = in2 - v;
    }
    __syncthreads();
    int excl = wsum[wv] + inc - val;
    if (i0 < NB) {
        off[i0] = excl;
        cur[i0] = 0;
        gbase[i0] = bstart[i0] + (int)table[(size_t)chunk * NB + i0];
    }
    if (i1 < NB) {
        off[i1] = excl + a;
        cur[i1] = 0;
        gbase[i1] = bstart[i1] + (int)table[(size_t)chunk * NB + i1];
    }
    __syncthreads();
    for (int i = t; i < m; i += PT) {
        int c = col[c0 + i];
        int bb = c >> BSH;
        int p = off[bb] + atomicAdd(&cur[bb], 1);
        unsigned meta = (unsigned)row[c0 + i] | ((unsigned)(c & (NPB - 1)) << 25);
        st2[p] = ((long long)__float_as_int(w[c0 + i]) << 32)
               | (long long)(unsigned long long)meta;
        bkt[p] = (unsigned short)bb;
    }
    __syncthreads();
    for (int i = t; i < m; i += PT) {
        int bb = bkt[i];
        long long v = st2[i];
        int pg = gbase[bb] + (i - off[bb]);
        reinterpret_cast<long long*>(part)[pg] = v;   // plain store: L2-mergeable
    }
}

// ---------------------------------------------------------------------------
// degv: per bucket, sort the WHOLE segment by node (u16 index sort in LDS),
// write back node-sorted + contiguous; emit row_ptr; weighted degree via
// fixed-point u32 LDS atomics (w * 2^18); dinv; scale h16 in place.
// ---------------------------------------------------------------------------
__global__ __launch_bounds__(1024)
void k_degv(float2* __restrict__ part, const int* __restrict__ bstart,
            const int* __restrict__ btot, int* __restrict__ rowptr,
            float* __restrict__ dinv, __half* __restrict__ h16, int n) {
    __shared__ long long sta[CAPB];          // 48 KB
    __shared__ unsigned short idx16[CAPB];   // 12 KB
    __shared__ int cnt[NPB], off2[NPB], cur[NPB];
    __shared__ unsigned int wsum[NPB];
    int b = blockIdx.x, t = threadIdx.x;
    int s = bstart[b];
    int tot = min(btot[b], CAPB);            // assumption: btot <= CAPB (27-sigma)
    long long* gp = reinterpret_cast<long long*>(part) + s;

    if (t < NPB) { cnt[t] = 0; wsum[t] = 0; }
    __syncthreads();
    // stage + count + fixed-point weight sum
    for (int i = t; i < tot; i += 1024) {
        long long q = __builtin_nontemporal_load(gp + i);
        sta[i] = q;
        int cl = (int)(((unsigned)q) >> 25);
        atomicAdd(&cnt[cl], 1);
        float wv = __int_as_float((int)(q >> 32));
        atomicAdd(&wsum[cl], (unsigned)__float2uint_rn(wv * 262144.f));
    }
    __syncthreads();
    if (t < NPB) {                // wave 0: 64-lane shfl scan
        int v = cnt[t];
        int inc = v;
        #pragma unroll
        for (int d = 1; d < 64; d <<= 1) {
            int o = __shfl_up(inc, d);
            if (t >= d) inc += o;
        }
        off2[t] = inc - v;
        cur[t] = inc - v;
        int node = b * NPB + t;
        if (node < n) rowptr[node] = s + inc - v;
    }
    __syncthreads();
    // place indices (u16) into sorted order
    for (int i = t; i < tot; i += 1024) {
        int cl = (int)(((unsigned)sta[i]) >> 25);
        int p = atomicAdd(&cur[cl], 1);
        idx16[p] = (unsigned short)i;
    }
    __syncthreads();
    // contiguous sorted write-back (full lines; NT fine)
    for (int i = t; i < tot; i += 1024)
        __builtin_nontemporal_store(sta[idx16[i]], gp + i);
    // dinv + h16 scale
    int g = t >> 4, l = t & 15;
    int node = b * NPB + g;
    if (node < n) {
        float di = rsqrtf(1.0f + (float)wsum[g] * (1.0f / 262144.f));
        if (l == 0) dinv[node] = di;
        size_t hoff = (size_t)node * NF + l;
        h16[hoff] = __float2half(__half2float(h16[hoff]) * di);
    }
}

// ---------------------------------------------------------------------------
// gather: pure CSR, no LDS, no barriers. One 16-lane group per node.
// PAIR-COOPERATIVE h-row loads: 2 lanes share one edge; lane parity p loads
// hp[p] (16B = features 8p..8p+7) -> ONE cache-line touch per edge (was 2).
// out[c] = dinv_c * (sum_e h'[r]*w + h'[c]) + bias, h' = h*dinv.
// ---------------------------------------------------------------------------
__global__ __launch_bounds__(256)
void k_gather(const float2* __restrict__ part, const int* __restrict__ rowptr,
              const float* __restrict__ dinv, const __half* __restrict__ h16,
              const float* __restrict__ bias, float* __restrict__ out,
              int n, int E) {
    int t = threadIdx.x;
    int gid = blockIdx.x * 16 + (t >> 4);   // node id
    int l = t & 15;
    if (gid >= n) return;
    int s = rowptr[gid];
    int e = (gid + 1 < n) ? rowptr[gid + 1] : E;
    const long long* sp = reinterpret_cast<const long long*>(part);
    int p = l & 1;                          // h-row half this lane loads
    float acc[8];
    #pragma unroll
    for (int j = 0; j < 8; ++j) acc[j] = 0.f;

    // 8 edges per group-iteration; pair (2j,2j+1) owns edge s + iter*8 + j
    for (int k = s + (l >> 1); k < e; k += 8) {
        long long q = __builtin_nontemporal_load(sp + k);
        int r = (int)(q & 0x1FFFFFFll);
        float wv = __int_as_float((int)(q >> 32));
        const float4* hp = reinterpret_cast<const float4*>(h16 + (size_t)r * NF);
        union { float4 v; __half2 h2[4]; } u;
        u.v = hp[p];
        #pragma unroll
        for (int j = 0; j < 4; ++j) {
            float2 f2 = __half22float2(u.h2[j]);
            acc[2 * j]     = fmaf(f2.x, wv, acc[2 * j]);
            acc[2 * j + 1] = fmaf(f2.y, wv, acc[2 * j + 1]);
        }
    }
    // reduce across the 8 same-parity lanes of the group (strides 2,4,8)
    #pragma unroll
    for (int j = 0; j < 8; ++j) {
        acc[j] += __shfl_xor(acc[j], 2);
        acc[j] += __shfl_xor(acc[j], 4);
        acc[j] += __shfl_xor(acc[j], 8);
    }
    // lane l writes feature f = p*8 + (l>>1); value = acc[l>>1] (static select)
    int f = p * 8 + (l >> 1);
    int sel = l >> 1;
    float av = 0.f;
    #pragma unroll
    for (int j = 0; j < 8; ++j) if (sel == j) av = acc[j];
    float dc = dinv[gid];
    float selfv = __half2float(h16[(size_t)gid * NF + f]);
    out[(size_t)gid * NF + f] = fmaf(dc, av + selfv, bias[f]);
}

// ==================== fallback (global-atomic scatter, f32) ================

__global__ void k_h1f(const float* __restrict__ x, const float* __restrict__ W1,
                      float* __restrict__ h, int n) {
    int i = blockIdx.x * blockDim.x + threadIdx.x;
    if (i >= n) return;
    const float4* xp = reinterpret_cast<const float4*>(x + (size_t)i * FI);
    float4 a = xp[0], b = xp[1];
    float xi[FI] = {a.x, a.y, a.z, a.w, b.x, b.y, b.z, b.w};
    #pragma unroll
    for (int f = 0; f < NF; ++f) {
        float acc = 0.f;
        #pragma unroll
        for (int k = 0; k < FI; ++k) acc = fmaf(xi[k], W1[k * NF + f], acc);
        h[(size_t)i * NF + f] = acc;
    }
}
__global__ void k_h2f(const float* __restrict__ src, const float* __restrict__ W2,
                      float* __restrict__ dst, int n) {
    int i = blockIdx.x * blockDim.x + threadIdx.x;
    if (i >= n) return;
    float hi[NF];
    #pragma unroll
    for (int f = 0; f < NF; ++f) hi[f] = fmaxf(src[(size_t)i * NF + f], 0.f);
    #pragma unroll
    for (int f = 0; f < NF; ++f) {
        float acc = 0.f;
        #pragma unroll
        for (int k = 0; k < NF; ++k) acc = fmaf(hi[k], W2[k * NF + f], acc);
        dst[(size_t)i * NF + f] = acc;
    }
}
__global__ void k_deg_init(float* __restrict__ deg, int n) {
    int i = blockIdx.x * blockDim.x + threadIdx.x;
    if (i < n) deg[i] = 1.0f;
}
__global__ void k_deg_acc(const int* __restrict__ col, const float* __restrict__ w,
                          float* __restrict__ deg, int E) {
    int e = blockIdx.x * blockDim.x + threadIdx.x;
    if (e < E) atomicAdd(&deg[col[e]], w[e]);
}
__global__ void k_dinv_ip(float* __restrict__ d, int n) {
    int i = blockIdx.x * blockDim.x + threadIdx.x;
    if (i < n) d[i] = rsqrtf(d[i]);
}
__global__ void k_init_out(const float* __restrict__ h, const float* __restrict__ dinv,
                           const float* __restrict__ bias, float* __restrict__ out, int n) {
    int i = blockIdx.x * blockDim.x + threadIdx.x;
    if (i >= n) return;
    float s = dinv[i] * dinv[i];
    #pragma unroll
    for (int f = 0; f < NF; ++f)
        out[(size_t)i * NF + f] = fmaf(h[(size_t)i * NF + f], s, bias[f]);
}
__global__ void k_scatter(const int* __restrict__ row, const int* __restrict__ col,
                          const float* __restrict__ w, const float* __restrict__ dinv,
                          const float* __restrict__ h, float* __restrict__ out, int E) {
    int e = blockIdx.x * blockDim.x + threadIdx.x;
    if (e >= E) return;
    int r = row[e], c = col[e];
    float norm = dinv[r] * w[e] * dinv[c];
    #pragma unroll
    for (int f = 0; f < NF; ++f)
        atomicAdd(&out[(size_t)c * NF + f], h[(size_t)r * NF + f] * norm);
}

// ===========================================================================

extern "C" void kernel_launch(void* const* d_in, const int* in_sizes, int n_in,
                              void* d_out, int out_size, void* d_ws, size_t ws_size,
                              hipStream_t stream) {
    const float* x  = (const float*)d_in[0];
    const int*   ei = (const int*)d_in[1];   // int32 (verified round 1)
    const float* w  = (const float*)d_in[2];
    const float* W1 = (const float*)d_in[3];
    const float* b1 = (const float*)d_in[4];
    const float* W2 = (const float*)d_in[5];
    const float* b2 = (const float*)d_in[6];
    float* out = (float*)d_out;

    const int n = in_sizes[0] / FI;          // 100000
    const int E = in_sizes[2];               // 6400000
    const int* row = ei;
    const int* col = ei + E;

    const int B  = 256;
    const int gn = (n + B - 1) / B;
    const int gE = (E + B - 1) / B;
    const int NB = (n + NPB - 1) / NPB;      // 1563
    const int NC = (E + CHUNK - 1) / CHUNK;  // 1563

    // ws layout (4B units): part(2E) | table(NC*NB u16 -> ceil/2 words)
    //   | btot(NB) | bstart(NB) | rowptr(n) | dinv(n) | h16(8n as halves)
    size_t tblw = ((size_t)NC * NB + 1) / 2;
    size_t base = (size_t)2 * E + tblw + 2 * (size_t)NB + 2 * (size_t)n;
    base = (base + 3) & ~(size_t)3;          // align h16 to 16 B
    size_t need = (base + 8 * (size_t)n) * 4;
    bool ok = (ws_size >= need) && (NB <= MAXNB) && (NC <= 2048) && (n < (1 << 25));

    if (ok) {
        float*          ws     = (float*)d_ws;
        float2*         part   = (float2*)ws;
        unsigned short* table  = (unsigned short*)(ws + 2 * (size_t)E);
        int*            btot   = (int*)(ws + 2 * (size_t)E + tblw);
        int*            bstart = btot + NB;
        int*            rowptr = bstart + NB;
        float*          dinv   = (float*)(rowptr + n);
        __half*         h16    = (__half*)(ws + base);

        k_h1<<<gn, B, 0, stream>>>(x, W1, h16, n);
        k_phist<<<NC, PT, 0, stream>>>(col, table, NB, E);
        k_scan_chunks<<<NB, 1024, 0, stream>>>(table, btot, NB, NC);
        k_scan_buckets<<<1, 1024, 0, stream>>>(btot, bstart, NB);
        k_pscatter<<<NC, PT, 0, stream>>>(row, col, w, table, bstart, part, NB, E);
        k_degv<<<NB, 1024, 0, stream>>>(part, bstart, btot, rowptr, dinv, h16, n);

        const int gg = (n + 15) / 16;
        k_gather<<<gg, B, 0, stream>>>(part, rowptr, dinv, h16, b1, out, n, E);
        k_h2<<<gn, B, 0, stream>>>(out, W2, dinv, h16, n);   // h2*dinv -> h16
        k_gather<<<gg, B, 0, stream>>>(part, rowptr, dinv, h16, b2, out, n, E);
    } else {
        // fallback: global-atomic scatter path (13.2 MB ws), known-correct
        float* ws   = (float*)d_ws;
        float* dinv = ws;
        float* h    = ws + (size_t)n;
        float* out1 = h + 16 * (size_t)n;

        k_h1f<<<gn, B, 0, stream>>>(x, W1, h, n);
        k_deg_init<<<gn, B, 0, stream>>>(dinv, n);
        k_deg_acc<<<gE, B, 0, stream>>>(col, w, dinv, E);
        k_dinv_ip<<<gn, B, 0, stream>>>(dinv, n);
        k_init_out<<<gn, B, 0, stream>>>(h, dinv, b1, out1, n);
        k_scatter<<<gE, B, 0, stream>>>(row, col, w, dinv, h, out1, E);
        k_h2f<<<gn, B, 0, stream>>>(out1, W2, out1, n);
        k_init_out<<<gn, B, 0, stream>>>(out1, dinv, b2, out, n);
        k_scatter<<<gE, B, 0, stream>>>(row, col, w, dinv, out1, out, E);
    }
}

// Round 18
// 267.245 us; speedup vs baseline: 1.0371x; 1.0371x over previous
//
#include <hip/hip_runtime.h>
#include <hip/hip_fp16.h>

#define NF 16          // feature width of h / output
#define FI 8           // input feature width
#define NPB 64         // nodes per bucket
#define BSH 6          // log2(NPB)
#define CHUNK 4096     // edges per partition chunk (fits LDS staging)
#define MAXNB 1600     // max buckets supported by LDS tables (NB=1563)
#define CAPB 6144      // max edges per bucket staged in degv LDS (mean 4096, sigma 64)
#define PT 1024        // pscatter/phist threads

// ---------------------------------------------------------------------------
// h1 = x @ W1  -> fp16 packed rows, UNscaled (degv scales by dinv later)
// ---------------------------------------------------------------------------
__global__ void k_h1(const float* __restrict__ x, const float* __restrict__ W1,
                     __half* __restrict__ h16, int n) {
    int i = blockIdx.x * blockDim.x + threadIdx.x;
    if (i >= n) return;
    const float4* xp = reinterpret_cast<const float4*>(x + (size_t)i * FI);
    float4 a = xp[0], b = xp[1];
    float xi[FI] = {a.x, a.y, a.z, a.w, b.x, b.y, b.z, b.w};
    float o[NF];
    #pragma unroll
    for (int f = 0; f < NF; ++f) {
        float acc = 0.f;
        #pragma unroll
        for (int k = 0; k < FI; ++k) acc = fmaf(xi[k], W1[k * NF + f], acc);
        o[f] = acc;
    }
    union { __half2 h2[8]; float4 v4[2]; } u;
    #pragma unroll
    for (int q = 0; q < 8; ++q) u.h2[q] = __floats2half2_rn(o[2 * q], o[2 * q + 1]);
    float4* hp = reinterpret_cast<float4*>(h16 + (size_t)i * NF);
    hp[0] = u.v4[0];
    hp[1] = u.v4[1];
}

// h2 = relu(src_f32) @ W2, scaled by dinv -> fp16 packed rows (h' = h2*dinv)
__global__ void k_h2(const float* __restrict__ src, const float* __restrict__ W2,
                     const float* __restrict__ dinv, __half* __restrict__ h16, int n) {
    int i = blockIdx.x * blockDim.x + threadIdx.x;
    if (i >= n) return;
    float hi[NF];
    const float4* ip = reinterpret_cast<const float4*>(src + (size_t)i * NF);
    #pragma unroll
    for (int q = 0; q < 4; ++q) {
        float4 v = ip[q];
        hi[q * 4 + 0] = fmaxf(v.x, 0.f);
        hi[q * 4 + 1] = fmaxf(v.y, 0.f);
        hi[q * 4 + 2] = fmaxf(v.z, 0.f);
        hi[q * 4 + 3] = fmaxf(v.w, 0.f);
    }
    float di = dinv[i];
    float o[NF];
    #pragma unroll
    for (int f = 0; f < NF; ++f) {
        float acc = 0.f;
        #pragma unroll
        for (int k = 0; k < NF; ++k) acc = fmaf(hi[k], W2[k * NF + f], acc);
        o[f] = acc * di;
    }
    union { __half2 h2[8]; float4 v4[2]; } u;
    #pragma unroll
    for (int q = 0; q < 8; ++q) u.h2[q] = __floats2half2_rn(o[2 * q], o[2 * q + 1]);
    float4* hp = reinterpret_cast<float4*>(h16 + (size_t)i * NF);
    hp[0] = u.v4[0];
    hp[1] = u.v4[1];
}

// ======================= radix-partition CSR build =========================
// table: u16, chunk-major table[chunk*NB + b]. Counts <= CHUNK; scanned
// offsets <= btot (~4400 for this input; assumption btot < 65536).

__global__ void k_phist(const int* __restrict__ col, unsigned short* __restrict__ table,
                        int NB, int E) {
    __shared__ int lh[MAXNB];
    int chunk = blockIdx.x, t = threadIdx.x;
    int c0 = chunk * CHUNK;
    int m = min(CHUNK, E - c0);
    for (int i = t; i < NB; i += PT) lh[i] = 0;
    __syncthreads();
    const int4* col4 = reinterpret_cast<const int4*>(col + c0);
    int m4 = m >> 2;
    for (int i = t; i < m4; i += PT) {
        int4 v = col4[i];
        atomicAdd(&lh[v.x >> BSH], 1);
        atomicAdd(&lh[v.y >> BSH], 1);
        atomicAdd(&lh[v.z >> BSH], 1);
        atomicAdd(&lh[v.w >> BSH], 1);
    }
    for (int i = (m4 << 2) + t; i < m; i += PT)
        atomicAdd(&lh[col[c0 + i] >> BSH], 1);
    __syncthreads();
    for (int b = t; b < NB; b += PT)
        table[(size_t)chunk * NB + b] = (unsigned short)lh[b];
}

// grid = NB blocks: exclusive scan of column b over NC chunks, shfl-based
__global__ void k_scan_chunks(unsigned short* __restrict__ table, int* __restrict__ btot,
                              int NB, int NC) {
    __shared__ int wsum[16];
    int b = blockIdx.x, t = threadIdx.x;
    int i0 = 2 * t, i1 = 2 * t + 1;
    int a = (i0 < NC) ? (int)table[(size_t)i0 * NB + b] : 0;
    int c = (i1 < NC) ? (int)table[(size_t)i1 * NB + b] : 0;
    int val = a + c;
    int lane = t & 63, wv = t >> 6;
    int inc = val;
    #pragma unroll
    for (int d = 1; d < 64; d <<= 1) {
        int o = __shfl_up(inc, d);
        if (lane >= d) inc += o;
    }
    if (lane == 63) wsum[wv] = inc;
    __syncthreads();
    if (t < 16) {
        int v = wsum[t];
        int in2 = v;
        #pragma unroll
        for (int d = 1; d < 16; d <<= 1) {
            int o = __shfl_up(in2, d);
            if (t >= d) in2 += o;
        }
        wsum[t] = in2 - v;   // exclusive
    }
    __syncthreads();
    int excl = wsum[wv] + inc - val;
    if (i0 < NC) table[(size_t)i0 * NB + b] = (unsigned short)excl;
    if (i1 < NC) table[(size_t)i1 * NB + b] = (unsigned short)(excl + a);
    if (t == 1023) btot[b] = excl + val;
}

// exclusive scan over bucket totals, shfl-based (2 elems/thread, NB<=2048)
__global__ void k_scan_buckets(const int* __restrict__ btot, int* __restrict__ bstart,
                               int NB) {
    __shared__ int wsum[16];
    int t = threadIdx.x;   // blockDim = 1024
    int i0 = 2 * t, i1 = 2 * t + 1;
    int a = (i0 < NB) ? btot[i0] : 0;
    int b = (i1 < NB) ? btot[i1] : 0;
    int val = a + b;
    int lane = t & 63, wv = t >> 6;
    int inc = val;
    #pragma unroll
    for (int d = 1; d < 64; d <<= 1) {
        int o = __shfl_up(inc, d);
        if (lane >= d) inc += o;
    }
    if (lane == 63) wsum[wv] = inc;
    __syncthreads();
    if (t < 16) {
        int v = wsum[t];
        int in2 = v;
        #pragma unroll
        for (int d = 1; d < 16; d <<= 1) {
            int o = __shfl_up(in2, d);
            if (t >= d) in2 += o;
        }
        wsum[t] = in2 - v;
    }
    __syncthreads();
    int excl = wsum[wv] + inc - val;
    if (i0 < NB) bstart[i0] = excl;
    if (i1 < NB) bstart[i1] = excl + a;
}

// partition scatter with in-LDS counting sort; flush in ascending global
// order with PLAIN stores (L2 merges cross-block runs — round 13 lesson).
// part[p] = { low32 = row | (col_local << 25), high32 = w bits }
__global__ __launch_bounds__(PT)
void k_pscatter(const int* __restrict__ row, const int* __restrict__ col,
                const float* __restrict__ w, const unsigned short* __restrict__ table,
                const int* __restrict__ bstart, float2* __restrict__ part,
                int NB, int E) {
    __shared__ long long st2[CHUNK];         // 32 KB
    __shared__ unsigned short bkt[CHUNK];    // 8 KB
    __shared__ int off[MAXNB], cur[MAXNB], gbase[MAXNB];  // 3 x 6.4 KB
    __shared__ int wsum[16];
    int chunk = blockIdx.x, t = threadIdx.x;
    int c0 = chunk * CHUNK;
    int m = min(CHUNK, E - c0);

    for (int i = t; i < NB; i += PT) cur[i] = 0;
    __syncthreads();
    for (int i = t; i < m; i += PT)
        atomicAdd(&cur[col[c0 + i] >> BSH], 1);
    __syncthreads();
    int i0 = 2 * t, i1 = 2 * t + 1;
    int a = (i0 < NB) ? cur[i0] : 0;
    int b = (i1 < NB) ? cur[i1] : 0;
    int val = a + b;
    int lane = t & 63, wv = t >> 6;
    int inc = val;
    #pragma unroll
    for (int d = 1; d < 64; d <<= 1) {
        int o = __shfl_up(inc, d);
        if (lane >= d) inc += o;
    }
    if (lane == 63) wsum[wv] = inc;
    __syncthreads();
    if (t < 16) {
        int v = wsum[t];
        int in2 = v;
        #pragma unroll
        for (int d = 1; d < 16; d <<= 1) {
            int o = __shfl_up(in2, d);
            if (t >= d) in2 += o;
        }
        wsum[t] = in2 - v;
    }
    __syncthreads();
    int excl = wsum[wv] + inc - val;
    if (i0 < NB) {
        off[i0] = excl;
        cur[i0] = 0;
        gbase[i0] = bstart[i0] + (int)table[(size_t)chunk * NB + i0];
    }
    if (i1 < NB) {
        off[i1] = excl + a;
        cur[i1] = 0;
        gbase[i1] = bstart[i1] + (int)table[(size_t)chunk * NB + i1];
    }
    __syncthreads();
    for (int i = t; i < m; i += PT) {
        int c = col[c0 + i];
        int bb = c >> BSH;
        int p = off[bb] + atomicAdd(&cur[bb], 1);
        unsigned meta = (unsigned)row[c0 + i] | ((unsigned)(c & (NPB - 1)) << 25);
        st2[p] = ((long long)__float_as_int(w[c0 + i]) << 32)
               | (long long)(unsigned long long)meta;
        bkt[p] = (unsigned short)bb;
    }
    __syncthreads();
    for (int i = t; i < m; i += PT) {
        int bb = bkt[i];
        long long v = st2[i];
        int pg = gbase[bb] + (i - off[bb]);
        reinterpret_cast<long long*>(part)[pg] = v;   // plain store: L2-mergeable
    }
}

// ---------------------------------------------------------------------------
// degv: per bucket, sort the WHOLE segment by node (u16 index sort in LDS),
// write back node-sorted + contiguous; emit row_ptr; weighted degree via
// fixed-point u32 LDS atomics (w * 2^18); dinv; scale h16 in place.
// ---------------------------------------------------------------------------
__global__ __launch_bounds__(1024)
void k_degv(float2* __restrict__ part, const int* __restrict__ bstart,
            const int* __restrict__ btot, int* __restrict__ rowptr,
            float* __restrict__ dinv, __half* __restrict__ h16, int n) {
    __shared__ long long sta[CAPB];          // 48 KB
    __shared__ unsigned short idx16[CAPB];   // 12 KB
    __shared__ int cnt[NPB], off2[NPB], cur[NPB];
    __shared__ unsigned int wsum[NPB];
    int b = blockIdx.x, t = threadIdx.x;
    int s = bstart[b];
    int tot = min(btot[b], CAPB);            // assumption: btot <= CAPB (27-sigma)
    long long* gp = reinterpret_cast<long long*>(part) + s;

    if (t < NPB) { cnt[t] = 0; wsum[t] = 0; }
    __syncthreads();
    // stage + count + fixed-point weight sum
    for (int i = t; i < tot; i += 1024) {
        long long q = __builtin_nontemporal_load(gp + i);
        sta[i] = q;
        int cl = (int)(((unsigned)q) >> 25);
        atomicAdd(&cnt[cl], 1);
        float wv = __int_as_float((int)(q >> 32));
        atomicAdd(&wsum[cl], (unsigned)__float2uint_rn(wv * 262144.f));
    }
    __syncthreads();
    if (t < NPB) {                // wave 0: 64-lane shfl scan
        int v = cnt[t];
        int inc = v;
        #pragma unroll
        for (int d = 1; d < 64; d <<= 1) {
            int o = __shfl_up(inc, d);
            if (t >= d) inc += o;
        }
        off2[t] = inc - v;
        cur[t] = inc - v;
        int node = b * NPB + t;
        if (node < n) rowptr[node] = s + inc - v;
    }
    __syncthreads();
    // place indices (u16) into sorted order
    for (int i = t; i < tot; i += 1024) {
        int cl = (int)(((unsigned)sta[i]) >> 25);
        int p = atomicAdd(&cur[cl], 1);
        idx16[p] = (unsigned short)i;
    }
    __syncthreads();
    // contiguous sorted write-back (full lines; NT fine)
    for (int i = t; i < tot; i += 1024)
        __builtin_nontemporal_store(sta[idx16[i]], gp + i);
    // dinv + h16 scale
    int g = t >> 4, l = t & 15;
    int node = b * NPB + g;
    if (node < n) {
        float di = rsqrtf(1.0f + (float)wsum[g] * (1.0f / 262144.f));
        if (l == 0) dinv[node] = di;
        size_t hoff = (size_t)node * NF + l;
        h16[hoff] = __float2half(__half2float(h16[hoff]) * di);
    }
}

// ---------------------------------------------------------------------------
// gather: pure CSR, no LDS, no barriers. One 16-lane group per node, each
// lane owns a full h-row per edge (round-14 layout). 4-DEEP SOFTWARE
// PIPELINE: 4 part loads + 8 h16 loads in flight per wave (was 1 chain).
// out[c] = dinv_c * (sum_e h'[r]*w + h'[c]) + bias, h' = h*dinv.
// ---------------------------------------------------------------------------
__device__ __forceinline__ void accum16(float* acc, float4 A, float4 B, float wv) {
    union { float4 v; __half2 h2[4]; } ua, ub;
    ua.v = A; ub.v = B;
    #pragma unroll
    for (int j = 0; j < 4; ++j) {
        float2 fa = __half22float2(ua.h2[j]);
        acc[2 * j]     = fmaf(fa.x, wv, acc[2 * j]);
        acc[2 * j + 1] = fmaf(fa.y, wv, acc[2 * j + 1]);
        float2 fb = __half22float2(ub.h2[j]);
        acc[8 + 2 * j]     = fmaf(fb.x, wv, acc[8 + 2 * j]);
        acc[8 + 2 * j + 1] = fmaf(fb.y, wv, acc[8 + 2 * j + 1]);
    }
}

__global__ __launch_bounds__(256)
void k_gather(const float2* __restrict__ part, const int* __restrict__ rowptr,
              const float* __restrict__ dinv, const __half* __restrict__ h16,
              const float* __restrict__ bias, float* __restrict__ out,
              int n, int E) {
    int t = threadIdx.x;
    int gid = blockIdx.x * 16 + (t >> 4);   // node id
    int l = t & 15;
    if (gid >= n) return;
    int s = rowptr[gid];
    int e = (gid + 1 < n) ? rowptr[gid + 1] : E;
    const long long* sp = reinterpret_cast<const long long*>(part);
    float acc[NF];
    #pragma unroll
    for (int j = 0; j < NF; ++j) acc[j] = 0.f;

    int k = s + l;
    // main: 4 edges per lane per trip, all loads batched for MLP
    while (k + 48 < e) {
        long long q0 = __builtin_nontemporal_load(sp + k);
        long long q1 = __builtin_nontemporal_load(sp + k + 16);
        long long q2 = __builtin_nontemporal_load(sp + k + 32);
        long long q3 = __builtin_nontemporal_load(sp + k + 48);
        int r0 = (int)(q0 & 0x1FFFFFFll);
        int r1 = (int)(q1 & 0x1FFFFFFll);
        int r2 = (int)(q2 & 0x1FFFFFFll);
        int r3 = (int)(q3 & 0x1FFFFFFll);
        const float4* h0 = reinterpret_cast<const float4*>(h16 + (size_t)r0 * NF);
        const float4* h1 = reinterpret_cast<const float4*>(h16 + (size_t)r1 * NF);
        const float4* h2p = reinterpret_cast<const float4*>(h16 + (size_t)r2 * NF);
        const float4* h3 = reinterpret_cast<const float4*>(h16 + (size_t)r3 * NF);
        float4 A0 = h0[0], B0 = h0[1];
        float4 A1 = h1[0], B1 = h1[1];
        float4 A2 = h2p[0], B2 = h2p[1];
        float4 A3 = h3[0], B3 = h3[1];
        float w0 = __int_as_float((int)(q0 >> 32));
        float w1 = __int_as_float((int)(q1 >> 32));
        float w2 = __int_as_float((int)(q2 >> 32));
        float w3 = __int_as_float((int)(q3 >> 32));
        accum16(acc, A0, B0, w0);
        accum16(acc, A1, B1, w1);
        accum16(acc, A2, B2, w2);
        accum16(acc, A3, B3, w3);
        k += 64;
    }
    // tail: one edge at a time
    while (k < e) {
        long long q = __builtin_nontemporal_load(sp + k);
        int r = (int)(q & 0x1FFFFFFll);
        float wv = __int_as_float((int)(q >> 32));
        const float4* hp = reinterpret_cast<const float4*>(h16 + (size_t)r * NF);
        accum16(acc, hp[0], hp[1], wv);
        k += 16;
    }
    // butterfly-reduce each feature across the 16 lanes of the group
    #pragma unroll
    for (int j = 0; j < NF; ++j) {
        #pragma unroll
        for (int d = 1; d < 16; d <<= 1)
            acc[j] += __shfl_xor(acc[j], d);
    }
    float dc = dinv[gid];
    float selfv = __half2float(h16[(size_t)gid * NF + l]);
    float av = 0.f;
    #pragma unroll
    for (int j = 0; j < NF; ++j) if (l == j) av = acc[j];   // static reg select
    out[(size_t)gid * NF + l] = fmaf(dc, av + selfv, bias[l]);
}

// ==================== fallback (global-atomic scatter, f32) ================

__global__ void k_h1f(const float* __restrict__ x, const float* __restrict__ W1,
                      float* __restrict__ h, int n) {
    int i = blockIdx.x * blockDim.x + threadIdx.x;
    if (i >= n) return;
    const float4* xp = reinterpret_cast<const float4*>(x + (size_t)i * FI);
    float4 a = xp[0], b = xp[1];
    float xi[FI] = {a.x, a.y, a.z, a.w, b.x, b.y, b.z, b.w};
    #pragma unroll
    for (int f = 0; f < NF; ++f) {
        float acc = 0.f;
        #pragma unroll
        for (int k = 0; k < FI; ++k) acc = fmaf(xi[k], W1[k * NF + f], acc);
        h[(size_t)i * NF + f] = acc;
    }
}
__global__ void k_h2f(const float* __restrict__ src, const float* __restrict__ W2,
                      float* __restrict__ dst, int n) {
    int i = blockIdx.x * blockDim.x + threadIdx.x;
    if (i >= n) return;
    float hi[NF];
    #pragma unroll
    for (int f = 0; f < NF; ++f) hi[f] = fmaxf(src[(size_t)i * NF + f], 0.f);
    #pragma unroll
    for (int f = 0; f < NF; ++f) {
        float acc = 0.f;
        #pragma unroll
        for (int k = 0; k < NF; ++k) acc = fmaf(hi[k], W2[k * NF + f], acc);
        dst[(size_t)i * NF + f] = acc;
    }
}
__global__ void k_deg_init(float* __restrict__ deg, int n) {
    int i = blockIdx.x * blockDim.x + threadIdx.x;
    if (i < n) deg[i] = 1.0f;
}
__global__ void k_deg_acc(const int* __restrict__ col, const float* __restrict__ w,
                          float* __restrict__ deg, int E) {
    int e = blockIdx.x * blockDim.x + threadIdx.x;
    if (e < E) atomicAdd(&deg[col[e]], w[e]);
}
__global__ void k_dinv_ip(float* __restrict__ d, int n) {
    int i = blockIdx.x * blockDim.x + threadIdx.x;
    if (i < n) d[i] = rsqrtf(d[i]);
}
__global__ void k_init_out(const float* __restrict__ h, const float* __restrict__ dinv,
                           const float* __restrict__ bias, float* __restrict__ out, int n) {
    int i = blockIdx.x * blockDim.x + threadIdx.x;
    if (i >= n) return;
    float s = dinv[i] * dinv[i];
    #pragma unroll
    for (int f = 0; f < NF; ++f)
        out[(size_t)i * NF + f] = fmaf(h[(size_t)i * NF + f], s, bias[f]);
}
__global__ void k_scatter(const int* __restrict__ row, const int* __restrict__ col,
                          const float* __restrict__ w, const float* __restrict__ dinv,
                          const float* __restrict__ h, float* __restrict__ out, int E) {
    int e = blockIdx.x * blockDim.x + threadIdx.x;
    if (e >= E) return;
    int r = row[e], c = col[e];
    float norm = dinv[r] * w[e] * dinv[c];
    #pragma unroll
    for (int f = 0; f < NF; ++f)
        atomicAdd(&out[(size_t)c * NF + f], h[(size_t)r * NF + f] * norm);
}

// ===========================================================================

extern "C" void kernel_launch(void* const* d_in, const int* in_sizes, int n_in,
                              void* d_out, int out_size, void* d_ws, size_t ws_size,
                              hipStream_t stream) {
    const float* x  = (const float*)d_in[0];
    const int*   ei = (const int*)d_in[1];   // int32 (verified round 1)
    const float* w  = (const float*)d_in[2];
    const float* W1 = (const float*)d_in[3];
    const float* b1 = (const float*)d_in[4];
    const float* W2 = (const float*)d_in[5];
    const float* b2 = (const float*)d_in[6];
    float* out = (float*)d_out;

    const int n = in_sizes[0] / FI;          // 100000
    const int E = in_sizes[2];               // 6400000
    const int* row = ei;
    const int* col = ei + E;

    const int B  = 256;
    const int gn = (n + B - 1) / B;
    const int gE = (E + B - 1) / B;
    const int NB = (n + NPB - 1) / NPB;      // 1563
    const int NC = (E + CHUNK - 1) / CHUNK;  // 1563

    // ws layout (4B units): part(2E) | table(NC*NB u16 -> ceil/2 words)
    //   | btot(NB) | bstart(NB) | rowptr(n) | dinv(n) | h16(8n as halves)
    size_t tblw = ((size_t)NC * NB + 1) / 2;
    size_t base = (size_t)2 * E + tblw + 2 * (size_t)NB + 2 * (size_t)n;
    base = (base + 3) & ~(size_t)3;          // align h16 to 16 B
    size_t need = (base + 8 * (size_t)n) * 4;
    bool ok = (ws_size >= need) && (NB <= MAXNB) && (NC <= 2048) && (n < (1 << 25));

    if (ok) {
        float*          ws     = (float*)d_ws;
        float2*         part   = (float2*)ws;
        unsigned short* table  = (unsigned short*)(ws + 2 * (size_t)E);
        int*            btot   = (int*)(ws + 2 * (size_t)E + tblw);
        int*            bstart = btot + NB;
        int*            rowptr = bstart + NB;
        float*          dinv   = (float*)(rowptr + n);
        __half*         h16    = (__half*)(ws + base);

        k_h1<<<gn, B, 0, stream>>>(x, W1, h16, n);
        k_phist<<<NC, PT, 0, stream>>>(col, table, NB, E);
        k_scan_chunks<<<NB, 1024, 0, stream>>>(table, btot, NB, NC);
        k_scan_buckets<<<1, 1024, 0, stream>>>(btot, bstart, NB);
        k_pscatter<<<NC, PT, 0, stream>>>(row, col, w, table, bstart, part, NB, E);
        k_degv<<<NB, 1024, 0, stream>>>(part, bstart, btot, rowptr, dinv, h16, n);

        const int gg = (n + 15) / 16;
        k_gather<<<gg, B, 0, stream>>>(part, rowptr, dinv, h16, b1, out, n, E);
        k_h2<<<gn, B, 0, stream>>>(out, W2, dinv, h16, n);   // h2*dinv -> h16
        k_gather<<<gg, B, 0, stream>>>(part, rowptr, dinv, h16, b2, out, n, E);
    } else {
        // fallback: global-atomic scatter path (13.2 MB ws), known-correct
        float* ws   = (float*)d_ws;
        float* dinv = ws;
        float* h    = ws + (size_t)n;
        float* out1 = h + 16 * (size_t)n;

        k_h1f<<<gn, B, 0, stream>>>(x, W1, h, n);
        k_deg_init<<<gn, B, 0, stream>>>(dinv, n);
        k_deg_acc<<<gE, B, 0, stream>>>(col, w, dinv, E);
        k_dinv_ip<<<gn, B, 0, stream>>>(dinv, n);
        k_init_out<<<gn, B, 0, stream>>>(h, dinv, b1, out1, n);
        k_scatter<<<gE, B, 0, stream>>>(row, col, w, dinv, h, out1, E);
        k_h2f<<<gn, B, 0, stream>>>(out1, W2, out1, n);
        k_init_out<<<gn, B, 0, stream>>>(out1, dinv, b2, out, n);
        k_scatter<<<gE, B, 0, stream>>>(row, col, w, dinv, out1, out, E);
    }
}

// Round 21
// 257.554 us; speedup vs baseline: 1.0761x; 1.0376x over previous
//
#include <hip/hip_runtime.h>
#include <hip/hip_fp16.h>

#define NF 16          // feature width of h / output
#define FI 8           // input feature width
#define NPB 64         // nodes per bucket
#define BSH 6          // log2(NPB)
#define CHUNK 6144     // edges per partition chunk (79KB LDS; 2 blocks/CU)
#define MAXNB 1600     // max buckets supported by LDS tables (NB=1563)
#define CAPB 6144      // max edges per bucket staged in degv LDS (mean 4096, sigma 64)
#define PT 1024        // pscatter/phist threads

// ---------------------------------------------------------------------------
// h1 = x @ W1  -> fp16 packed rows, UNscaled (degv scales by dinv later)
// ---------------------------------------------------------------------------
__global__ void k_h1(const float* __restrict__ x, const float* __restrict__ W1,
                     __half* __restrict__ h16, int n) {
    int i = blockIdx.x * blockDim.x + threadIdx.x;
    if (i >= n) return;
    const float4* xp = reinterpret_cast<const float4*>(x + (size_t)i * FI);
    float4 a = xp[0], b = xp[1];
    float xi[FI] = {a.x, a.y, a.z, a.w, b.x, b.y, b.z, b.w};
    float o[NF];
    #pragma unroll
    for (int f = 0; f < NF; ++f) {
        float acc = 0.f;
        #pragma unroll
        for (int k = 0; k < FI; ++k) acc = fmaf(xi[k], W1[k * NF + f], acc);
        o[f] = acc;
    }
    union { __half2 h2[8]; float4 v4[2]; } u;
    #pragma unroll
    for (int q = 0; q < 8; ++q) u.h2[q] = __floats2half2_rn(o[2 * q], o[2 * q + 1]);
    float4* hp = reinterpret_cast<float4*>(h16 + (size_t)i * NF);
    hp[0] = u.v4[0];
    hp[1] = u.v4[1];
}

// h2 = relu(src_f32) @ W2, scaled by dinv -> fp16 packed rows (h' = h2*dinv)
__global__ void k_h2(const float* __restrict__ src, const float* __restrict__ W2,
                     const float* __restrict__ dinv, __half* __restrict__ h16, int n) {
    int i = blockIdx.x * blockDim.x + threadIdx.x;
    if (i >= n) return;
    float hi[NF];
    const float4* ip = reinterpret_cast<const float4*>(src + (size_t)i * NF);
    #pragma unroll
    for (int q = 0; q < 4; ++q) {
        float4 v = ip[q];
        hi[q * 4 + 0] = fmaxf(v.x, 0.f);
        hi[q * 4 + 1] = fmaxf(v.y, 0.f);
        hi[q * 4 + 2] = fmaxf(v.z, 0.f);
        hi[q * 4 + 3] = fmaxf(v.w, 0.f);
    }
    float di = dinv[i];
    float o[NF];
    #pragma unroll
    for (int f = 0; f < NF; ++f) {
        float acc = 0.f;
        #pragma unroll
        for (int k = 0; k < NF; ++k) acc = fmaf(hi[k], W2[k * NF + f], acc);
        o[f] = acc * di;
    }
    union { __half2 h2[8]; float4 v4[2]; } u;
    #pragma unroll
    for (int q = 0; q < 8; ++q) u.h2[q] = __floats2half2_rn(o[2 * q], o[2 * q + 1]);
    float4* hp = reinterpret_cast<float4*>(h16 + (size_t)i * NF);
    hp[0] = u.v4[0];
    hp[1] = u.v4[1];
}

// ======================= radix-partition CSR build =========================
// table: u16, chunk-major table[chunk*NB + b]. Counts <= CHUNK; scanned
// offsets <= btot (~4400 for this input; assumption btot < 65536).

__global__ void k_phist(const int* __restrict__ col, unsigned short* __restrict__ table,
                        int NB, int E) {
    __shared__ int lh[MAXNB];
    int chunk = blockIdx.x, t = threadIdx.x;
    int c0 = chunk * CHUNK;
    int m = min(CHUNK, E - c0);
    for (int i = t; i < NB; i += PT) lh[i] = 0;
    __syncthreads();
    const int4* col4 = reinterpret_cast<const int4*>(col + c0);
    int m4 = m >> 2;
    for (int i = t; i < m4; i += PT) {
        int4 v = col4[i];
        atomicAdd(&lh[v.x >> BSH], 1);
        atomicAdd(&lh[v.y >> BSH], 1);
        atomicAdd(&lh[v.z >> BSH], 1);
        atomicAdd(&lh[v.w >> BSH], 1);
    }
    for (int i = (m4 << 2) + t; i < m; i += PT)
        atomicAdd(&lh[col[c0 + i] >> BSH], 1);
    __syncthreads();
    for (int b = t; b < NB; b += PT)
        table[(size_t)chunk * NB + b] = (unsigned short)lh[b];
}

// grid = NB blocks: exclusive scan of column b over NC chunks, shfl-based
__global__ void k_scan_chunks(unsigned short* __restrict__ table, int* __restrict__ btot,
                              int NB, int NC) {
    __shared__ int wsum[16];
    int b = blockIdx.x, t = threadIdx.x;
    int i0 = 2 * t, i1 = 2 * t + 1;
    int a = (i0 < NC) ? (int)table[(size_t)i0 * NB + b] : 0;
    int c = (i1 < NC) ? (int)table[(size_t)i1 * NB + b] : 0;
    int val = a + c;
    int lane = t & 63, wv = t >> 6;
    int inc = val;
    #pragma unroll
    for (int d = 1; d < 64; d <<= 1) {
        int o = __shfl_up(inc, d);
        if (lane >= d) inc += o;
    }
    if (lane == 63) wsum[wv] = inc;
    __syncthreads();
    if (t < 16) {
        int v = wsum[t];
        int in2 = v;
        #pragma unroll
        for (int d = 1; d < 16; d <<= 1) {
            int o = __shfl_up(in2, d);
            if (t >= d) in2 += o;
        }
        wsum[t] = in2 - v;   // exclusive
    }
    __syncthreads();
    int excl = wsum[wv] + inc - val;
    if (i0 < NC) table[(size_t)i0 * NB + b] = (unsigned short)excl;
    if (i1 < NC) table[(size_t)i1 * NB + b] = (unsigned short)(excl + a);
    if (t == 1023) btot[b] = excl + val;
}

// exclusive scan over bucket totals, shfl-based (2 elems/thread, NB<=2048)
__global__ void k_scan_buckets(const int* __restrict__ btot, int* __restrict__ bstart,
                               int NB) {
    __shared__ int wsum[16];
    int t = threadIdx.x;   // blockDim = 1024
    int i0 = 2 * t, i1 = 2 * t + 1;
    int a = (i0 < NB) ? btot[i0] : 0;
    int b = (i1 < NB) ? btot[i1] : 0;
    int val = a + b;
    int lane = t & 63, wv = t >> 6;
    int inc = val;
    #pragma unroll
    for (int d = 1; d < 64; d <<= 1) {
        int o = __shfl_up(inc, d);
        if (lane >= d) inc += o;
    }
    if (lane == 63) wsum[wv] = inc;
    __syncthreads();
    if (t < 16) {
        int v = wsum[t];
        int in2 = v;
        #pragma unroll
        for (int d = 1; d < 16; d <<= 1) {
            int o = __shfl_up(in2, d);
            if (t >= d) in2 += o;
        }
        wsum[t] = in2 - v;
    }
    __syncthreads();
    int excl = wsum[wv] + inc - val;
    if (i0 < NB) bstart[i0] = excl;
    if (i1 < NB) bstart[i1] = excl + a;
}

// partition scatter with in-LDS counting sort; flush in ascending global
// order with PLAIN stores (L2 merges cross-block runs — round 13 lesson).
// CHUNK=6144: 33% fewer chunk-boundary partial sectors (write amp ~ NB*NC).
// part[p] = { low32 = row | (col_local << 25), high32 = w bits }
__global__ __launch_bounds__(PT)
void k_pscatter(const int* __restrict__ row, const int* __restrict__ col,
                const float* __restrict__ w, const unsigned short* __restrict__ table,
                const int* __restrict__ bstart, float2* __restrict__ part,
                int NB, int E) {
    __shared__ long long st2[CHUNK];         // 48 KB
    __shared__ unsigned short bkt[CHUNK];    // 12 KB
    __shared__ int off[MAXNB], cur[MAXNB], gbase[MAXNB];  // 3 x 6.4 KB
    __shared__ int wsum[16];
    int chunk = blockIdx.x, t = threadIdx.x;
    int c0 = chunk * CHUNK;
    int m = min(CHUNK, E - c0);

    for (int i = t; i < NB; i += PT) cur[i] = 0;
    __syncthreads();
    for (int i = t; i < m; i += PT)
        atomicAdd(&cur[col[c0 + i] >> BSH], 1);
    __syncthreads();
    int i0 = 2 * t, i1 = 2 * t + 1;
    int a = (i0 < NB) ? cur[i0] : 0;
    int b = (i1 < NB) ? cur[i1] : 0;
    int val = a + b;
    int lane = t & 63, wv = t >> 6;
    int inc = val;
    #pragma unroll
    for (int d = 1; d < 64; d <<= 1) {
        int o = __shfl_up(inc, d);
        if (lane >= d) inc += o;
    }
    if (lane == 63) wsum[wv] = inc;
    __syncthreads();
    if (t < 16) {
        int v = wsum[t];
        int in2 = v;
        #pragma unroll
        for (int d = 1; d < 16; d <<= 1) {
            int o = __shfl_up(in2, d);
            if (t >= d) in2 += o;
        }
        wsum[t] = in2 - v;
    }
    __syncthreads();
    int excl = wsum[wv] + inc - val;
    if (i0 < NB) {
        off[i0] = excl;
        cur[i0] = 0;
        gbase[i0] = bstart[i0] + (int)table[(size_t)chunk * NB + i0];
    }
    if (i1 < NB) {
        off[i1] = excl + a;
        cur[i1] = 0;
        gbase[i1] = bstart[i1] + (int)table[(size_t)chunk * NB + i1];
    }
    __syncthreads();
    for (int i = t; i < m; i += PT) {
        int c = col[c0 + i];
        int bb = c >> BSH;
        int p = off[bb] + atomicAdd(&cur[bb], 1);
        unsigned meta = (unsigned)row[c0 + i] | ((unsigned)(c & (NPB - 1)) << 25);
        st2[p] = ((long long)__float_as_int(w[c0 + i]) << 32)
               | (long long)(unsigned long long)meta;
        bkt[p] = (unsigned short)bb;
    }
    __syncthreads();
    for (int i = t; i < m; i += PT) {
        int bb = bkt[i];
        long long v = st2[i];
        int pg = gbase[bb] + (i - off[bb]);
        reinterpret_cast<long long*>(part)[pg] = v;   // plain store: L2-mergeable
    }
}

// ---------------------------------------------------------------------------
// degv: per bucket, sort the WHOLE segment by node (u16 index sort in LDS),
// write back node-sorted + contiguous; emit row_ptr; weighted degree via
// fixed-point u32 LDS atomics (w * 2^18); dinv; scale h16 in place.
// ---------------------------------------------------------------------------
__global__ __launch_bounds__(1024)
void k_degv(float2* __restrict__ part, const int* __restrict__ bstart,
            const int* __restrict__ btot, int* __restrict__ rowptr,
            float* __restrict__ dinv, __half* __restrict__ h16, int n) {
    __shared__ long long sta[CAPB];          // 48 KB
    __shared__ unsigned short idx16[CAPB];   // 12 KB
    __shared__ int cnt[NPB], off2[NPB], cur[NPB];
    __shared__ unsigned int wsum[NPB];
    int b = blockIdx.x, t = threadIdx.x;
    int s = bstart[b];
    int tot = min(btot[b], CAPB);            // assumption: btot <= CAPB (27-sigma)
    long long* gp = reinterpret_cast<long long*>(part) + s;

    if (t < NPB) { cnt[t] = 0; wsum[t] = 0; }
    __syncthreads();
    // stage + count + fixed-point weight sum
    for (int i = t; i < tot; i += 1024) {
        long long q = __builtin_nontemporal_load(gp + i);
        sta[i] = q;
        int cl = (int)(((unsigned)q) >> 25);
        atomicAdd(&cnt[cl], 1);
        float wv = __int_as_float((int)(q >> 32));
        atomicAdd(&wsum[cl], (unsigned)__float2uint_rn(wv * 262144.f));
    }
    __syncthreads();
    if (t < NPB) {                // wave 0: 64-lane shfl scan
        int v = cnt[t];
        int inc = v;
        #pragma unroll
        for (int d = 1; d < 64; d <<= 1) {
            int o = __shfl_up(inc, d);
            if (t >= d) inc += o;
        }
        off2[t] = inc - v;
        cur[t] = inc - v;
        int node = b * NPB + t;
        if (node < n) rowptr[node] = s + inc - v;
    }
    __syncthreads();
    // place indices (u16) into sorted order
    for (int i = t; i < tot; i += 1024) {
        int cl = (int)(((unsigned)sta[i]) >> 25);
        int p = atomicAdd(&cur[cl], 1);
        idx16[p] = (unsigned short)i;
    }
    __syncthreads();
    // contiguous sorted write-back (full lines; NT fine)
    for (int i = t; i < tot; i += 1024)
        __builtin_nontemporal_store(sta[idx16[i]], gp + i);
    // dinv + h16 scale
    int g = t >> 4, l = t & 15;
    int node = b * NPB + g;
    if (node < n) {
        float di = rsqrtf(1.0f + (float)wsum[g] * (1.0f / 262144.f));
        if (l == 0) dinv[node] = di;
        size_t hoff = (size_t)node * NF + l;
        h16[hoff] = __float2half(__half2float(h16[hoff]) * di);
    }
}

// ---------------------------------------------------------------------------
// gather: pure CSR, no LDS, no barriers. One 16-lane group per node, full
// h-row per lane. launch_bounds(256,8): request 32 waves/CU — gather is
// L2-request-rate bound; TLP is the only remaining lever.
// out[c] = dinv_c * (sum_e h'[r]*w + h'[c]) + bias, h' = h*dinv.
// ---------------------------------------------------------------------------
__device__ __forceinline__ void accum16(float* acc, float4 A, float4 B, float wv) {
    union { float4 v; __half2 h2[4]; } ua, ub;
    ua.v = A; ub.v = B;
    #pragma unroll
    for (int j = 0; j < 4; ++j) {
        float2 fa = __half22float2(ua.h2[j]);
        acc[2 * j]     = fmaf(fa.x, wv, acc[2 * j]);
        acc[2 * j + 1] = fmaf(fa.y, wv, acc[2 * j + 1]);
        float2 fb = __half22float2(ub.h2[j]);
        acc[8 + 2 * j]     = fmaf(fb.x, wv, acc[8 + 2 * j]);
        acc[8 + 2 * j + 1] = fmaf(fb.y, wv, acc[8 + 2 * j + 1]);
    }
}

__global__ __launch_bounds__(256, 8)
void k_gather(const float2* __restrict__ part, const int* __restrict__ rowptr,
              const float* __restrict__ dinv, const __half* __restrict__ h16,
              const float* __restrict__ bias, float* __restrict__ out,
              int n, int E) {
    int t = threadIdx.x;
    int gid = blockIdx.x * 16 + (t >> 4);   // node id
    int l = t & 15;
    if (gid >= n) return;
    int s = rowptr[gid];
    int e = (gid + 1 < n) ? rowptr[gid + 1] : E;
    const long long* sp = reinterpret_cast<const long long*>(part);
    float acc[NF];
    #pragma unroll
    for (int j = 0; j < NF; ++j) acc[j] = 0.f;

    int k = s + l;
    while (k + 16 < e) {
        long long q0 = __builtin_nontemporal_load(sp + k);
        long long q1 = __builtin_nontemporal_load(sp + k + 16);
        int r0 = (int)(q0 & 0x1FFFFFFll);
        int r1 = (int)(q1 & 0x1FFFFFFll);
        const float4* h0 = reinterpret_cast<const float4*>(h16 + (size_t)r0 * NF);
        const float4* h1 = reinterpret_cast<const float4*>(h16 + (size_t)r1 * NF);
        float4 A0 = h0[0], B0 = h0[1];
        float4 A1 = h1[0], B1 = h1[1];
        float w0 = __int_as_float((int)(q0 >> 32));
        float w1 = __int_as_float((int)(q1 >> 32));
        accum16(acc, A0, B0, w0);
        accum16(acc, A1, B1, w1);
        k += 32;
    }
    while (k < e) {
        long long q = __builtin_nontemporal_load(sp + k);
        int r = (int)(q & 0x1FFFFFFll);
        float wv = __int_as_float((int)(q >> 32));
        const float4* hp = reinterpret_cast<const float4*>(h16 + (size_t)r * NF);
        accum16(acc, hp[0], hp[1], wv);
        k += 16;
    }
    // butterfly-reduce each feature across the 16 lanes of the group
    #pragma unroll
    for (int j = 0; j < NF; ++j) {
        #pragma unroll
        for (int d = 1; d < 16; d <<= 1)
            acc[j] += __shfl_xor(acc[j], d);
    }
    float dc = dinv[gid];
    float selfv = __half2float(h16[(size_t)gid * NF + l]);
    float av = 0.f;
    #pragma unroll
    for (int j = 0; j < NF; ++j) if (l == j) av = acc[j];   // static reg select
    out[(size_t)gid * NF + l] = fmaf(dc, av + selfv, bias[l]);
}

// ==================== fallback (global-atomic scatter, f32) ================

__global__ void k_h1f(const float* __restrict__ x, const float* __restrict__ W1,
                      float* __restrict__ h, int n) {
    int i = blockIdx.x * blockDim.x + threadIdx.x;
    if (i >= n) return;
    const float4* xp = reinterpret_cast<const float4*>(x + (size_t)i * FI);
    float4 a = xp[0], b = xp[1];
    float xi[FI] = {a.x, a.y, a.z, a.w, b.x, b.y, b.z, b.w};
    #pragma unroll
    for (int f = 0; f < NF; ++f) {
        float acc = 0.f;
        #pragma unroll
        for (int k = 0; k < FI; ++k) acc = fmaf(xi[k], W1[k * NF + f], acc);
        h[(size_t)i * NF + f] = acc;
    }
}
__global__ void k_h2f(const float* __restrict__ src, const float* __restrict__ W2,
                      float* __restrict__ dst, int n) {
    int i = blockIdx.x * blockDim.x + threadIdx.x;
    if (i >= n) return;
    float hi[NF];
    #pragma unroll
    for (int f = 0; f < NF; ++f) hi[f] = fmaxf(src[(size_t)i * NF + f], 0.f);
    #pragma unroll
    for (int f = 0; f < NF; ++f) {
        float acc = 0.f;
        #pragma unroll
        for (int k = 0; k < NF; ++k) acc = fmaf(hi[k], W2[k * NF + f], acc);
        dst[(size_t)i * NF + f] = acc;
    }
}
__global__ void k_deg_init(float* __restrict__ deg, int n) {
    int i = blockIdx.x * blockDim.x + threadIdx.x;
    if (i < n) deg[i] = 1.0f;
}
__global__ void k_deg_acc(const int* __restrict__ col, const float* __restrict__ w,
                          float* __restrict__ deg, int E) {
    int e = blockIdx.x * blockDim.x + threadIdx.x;
    if (e < E) atomicAdd(&deg[col[e]], w[e]);
}
__global__ void k_dinv_ip(float* __restrict__ d, int n) {
    int i = blockIdx.x * blockDim.x + threadIdx.x;
    if (i < n) d[i] = rsqrtf(d[i]);
}
__global__ void k_init_out(const float* __restrict__ h, const float* __restrict__ dinv,
                           const float* __restrict__ bias, float* __restrict__ out, int n) {
    int i = blockIdx.x * blockDim.x + threadIdx.x;
    if (i >= n) return;
    float s = dinv[i] * dinv[i];
    #pragma unroll
    for (int f = 0; f < NF; ++f)
        out[(size_t)i * NF + f] = fmaf(h[(size_t)i * NF + f], s, bias[f]);
}
__global__ void k_scatter(const int* __restrict__ row, const int* __restrict__ col,
                          const float* __restrict__ w, const float* __restrict__ dinv,
                          const float* __restrict__ h, float* __restrict__ out, int E) {
    int e = blockIdx.x * blockDim.x + threadIdx.x;
    if (e >= E) return;
    int r = row[e], c = col[e];
    float norm = dinv[r] * w[e] * dinv[c];
    #pragma unroll
    for (int f = 0; f < NF; ++f)
        atomicAdd(&out[(size_t)c * NF + f], h[(size_t)r * NF + f] * norm);
}

// ===========================================================================

extern "C" void kernel_launch(void* const* d_in, const int* in_sizes, int n_in,
                              void* d_out, int out_size, void* d_ws, size_t ws_size,
                              hipStream_t stream) {
    const float* x  = (const float*)d_in[0];
    const int*   ei = (const int*)d_in[1];   // int32 (verified round 1)
    const float* w  = (const float*)d_in[2];
    const float* W1 = (const float*)d_in[3];
    const float* b1 = (const float*)d_in[4];
    const float* W2 = (const float*)d_in[5];
    const float* b2 = (const float*)d_in[6];
    float* out = (float*)d_out;

    const int n = in_sizes[0] / FI;          // 100000
    const int E = in_sizes[2];               // 6400000
    const int* row = ei;
    const int* col = ei + E;

    const int B  = 256;
    const int gn = (n + B - 1) / B;
    const int gE = (E + B - 1) / B;
    const int NB = (n + NPB - 1) / NPB;      // 1563
    const int NC = (E + CHUNK - 1) / CHUNK;  // 1042

    // ws layout (4B units): part(2E) | table(NC*NB u16 -> ceil/2 words)
    //   | btot(NB) | bstart(NB) | rowptr(n) | dinv(n) | h16(8n as halves)
    size_t tblw = ((size_t)NC * NB + 1) / 2;
    size_t base = (size_t)2 * E + tblw + 2 * (size_t)NB + 2 * (size_t)n;
    base = (base + 3) & ~(size_t)3;          // align h16 to 16 B
    size_t need = (base + 8 * (size_t)n) * 4;
    bool ok = (ws_size >= need) && (NB <= MAXNB) && (NC <= 2048) && (n < (1 << 25));

    if (ok) {
        float*          ws     = (float*)d_ws;
        float2*         part   = (float2*)ws;
        unsigned short* table  = (unsigned short*)(ws + 2 * (size_t)E);
        int*            btot   = (int*)(ws + 2 * (size_t)E + tblw);
        int*            bstart = btot + NB;
        int*            rowptr = bstart + NB;
        float*          dinv   = (float*)(rowptr + n);
        __half*         h16    = (__half*)(ws + base);

        k_h1<<<gn, B, 0, stream>>>(x, W1, h16, n);
        k_phist<<<NC, PT, 0, stream>>>(col, table, NB, E);
        k_scan_chunks<<<NB, 1024, 0, stream>>>(table, btot, NB, NC);
        k_scan_buckets<<<1, 1024, 0, stream>>>(btot, bstart, NB);
        k_pscatter<<<NC, PT, 0, stream>>>(row, col, w, table, bstart, part, NB, E);
        k_degv<<<NB, 1024, 0, stream>>>(part, bstart, btot, rowptr, dinv, h16, n);

        const int gg = (n + 15) / 16;
        k_gather<<<gg, B, 0, stream>>>(part, rowptr, dinv, h16, b1, out, n, E);
        k_h2<<<gn, B, 0, stream>>>(out, W2, dinv, h16, n);   // h2*dinv -> h16
        k_gather<<<gg, B, 0, stream>>>(part, rowptr, dinv, h16, b2, out, n, E);
    } else {
        // fallback: global-atomic scatter path (13.2 MB ws), known-correct
        float* ws   = (float*)d_ws;
        float* dinv = ws;
        float* h    = ws + (size_t)n;
        float* out1 = h + 16 * (size_t)n;

        k_h1f<<<gn, B, 0, stream>>>(x, W1, h, n);
        k_deg_init<<<gn, B, 0, stream>>>(dinv, n);
        k_deg_acc<<<gE, B, 0, stream>>>(col, w, dinv, E);
        k_dinv_ip<<<gn, B, 0, stream>>>(dinv, n);
        k_init_out<<<gn, B, 0, stream>>>(h, dinv, b1, out1, n);
        k_scatter<<<gE, B, 0, stream>>>(row, col, w, dinv, h, out1, E);
        k_h2f<<<gn, B, 0, stream>>>(out1, W2, out1, n);
        k_init_out<<<gn, B, 0, stream>>>(out1, dinv, b2, out, n);
        k_scatter<<<gE, B, 0, stream>>>(row, col, w, dinv, out1, out, E);
    }
}